// Round 11
// baseline (504.461 us; speedup 1.0000x reference)
//
#include <hip/hip_runtime.h>

typedef unsigned int u32;
typedef unsigned short u16;

typedef __attribute__((ext_vector_type(8))) __bf16 bf16x8;
typedef __attribute__((ext_vector_type(4))) float f32x4;
typedef __attribute__((ext_vector_type(2))) float f32x2;
typedef __attribute__((ext_vector_type(4))) u32 u32x4;

#define N_NODES 32768
#define N_EDGES 524288
#define DIM 512
#define N_GRAPHS 512
#define ECAP 1536   // staged edges per 64-row block (12 KB); mean 1024, +16 sigma
#define NB_TR 1536

#define MFMA16 __builtin_amdgcn_mfma_f32_16x16x32_bf16

__device__ __forceinline__ u16 f2b(float f) {
  union { float f; u32 u; } v; v.f = f;
  u32 r = v.u + 0x7FFFu + ((v.u >> 16) & 1u);   // RNE
  return (u16)(r >> 16);
}
__device__ __forceinline__ u32 pack2(float a, float b) {
  return (u32)f2b(a) | ((u32)f2b(b) << 16);
}
__device__ __forceinline__ float blo(u32 u) { union { u32 u; float f; } v; v.u = u << 16; return v.f; }
__device__ __forceinline__ float bhi(u32 u) { union { u32 u; float f; } v; v.u = u & 0xFFFF0000u; return v.f; }
__device__ __forceinline__ float b2f(u16 u) { union { u32 u; float f; } v; v.u = ((u32)u) << 16; return v.f; }

__device__ __forceinline__ void async16(const void* g, void* l) {
  __builtin_amdgcn_global_load_lds(
      (const __attribute__((address_space(1))) u32*)g,
      (__attribute__((address_space(3))) u32*)l, 16, 0, 0);
}

__device__ __forceinline__ void acc8(f32x2* a, u32x4 raw, float v) {
  f32x2 v2 = {v, v};
  a[0] += v2 * f32x2{blo(raw.x), bhi(raw.x)};
  a[1] += v2 * f32x2{blo(raw.y), bhi(raw.y)};
  a[2] += v2 * f32x2{blo(raw.z), bhi(raw.z)};
  a[3] += v2 * f32x2{blo(raw.w), bhi(raw.w)};
}

// ---------------- prep: 6 weight transposes + dst histogram ----------------
struct WPack {
  const float* src[6];
  u16* dst[6];
};
__global__ __launch_bounds__(256)
void k_prep(WPack wp, const int* __restrict__ dstv, int* __restrict__ counts) {
  __shared__ float tile[32][33];
  const int bid = blockIdx.x, tid = threadIdx.x;
  if (bid < NB_TR) {
    int bz = bid >> 8, rem = bid & 255, by = rem >> 4, bx = rem & 15;
    const float* W = wp.src[bz];
    u16* Wt = wp.dst[bz];
    int tx = tid & 31, ty = tid >> 5;
    int bx32 = bx * 32, by32 = by * 32;
    #pragma unroll
    for (int i = 0; i < 4; i++)
      tile[ty + 8 * i][tx] = W[(size_t)(by32 + ty + 8 * i) * DIM + bx32 + tx];
    __syncthreads();
    #pragma unroll
    for (int i = 0; i < 4; i++)
      Wt[(size_t)(bx32 + ty + 8 * i) * DIM + by32 + tx] = f2b(tile[tx][ty + 8 * i]);
  } else {
    int i = (bid - NB_TR) * 256 + tid;
    atomicAdd(&counts[dstv[i]], 1);
  }
}

// ---------------- CSR scan (int4-vectorized) ----------------
__global__ void k_scan(const int* __restrict__ counts, int* __restrict__ offsets,
                       int* __restrict__ cursor) {
  __shared__ int part[1024];
  int t = threadIdx.x;
  const int4* c4 = (const int4*)counts;
  int4 cv[8];
  #pragma unroll
  for (int j = 0; j < 8; j++) cv[j] = c4[t * 8 + j];
  int loc[32];
  int s = 0;
  #pragma unroll
  for (int j = 0; j < 8; j++) {
    loc[4 * j + 0] = s; s += cv[j].x;
    loc[4 * j + 1] = s; s += cv[j].y;
    loc[4 * j + 2] = s; s += cv[j].z;
    loc[4 * j + 3] = s; s += cv[j].w;
  }
  part[t] = s;
  __syncthreads();
  for (int off = 1; off < 1024; off <<= 1) {
    int v = (t >= off) ? part[t - off] : 0;
    __syncthreads();
    part[t] += v;
    __syncthreads();
  }
  int excl = (t == 0) ? 0 : part[t - 1];
  #pragma unroll
  for (int j = 0; j < 8; j++) {
    int4 o = make_int4(excl + loc[4 * j], excl + loc[4 * j + 1],
                       excl + loc[4 * j + 2], excl + loc[4 * j + 3]);
    ((int4*)offsets)[t * 8 + j] = o;
    ((int4*)cursor)[t * 8 + j] = o;
  }
  if (t == 1023) offsets[N_NODES] = excl + s;
}

__global__ void k_fill(const int* __restrict__ src, const int* __restrict__ dst,
                       const float* __restrict__ vals, int* __restrict__ cursor,
                       int2* __restrict__ epack) {
  int i = blockIdx.x * 256 + threadIdx.x;
  if (i >= N_EDGES) return;
  int d = dst[i];
  int p = atomicAdd(&cursor[d], 1);
  epack[p] = make_int2(src[i], __float_as_int(vals[i]));
}

// ---------------- big GEMM with fused f32->bf16 A-conversion ----------------
// C[M,N] = bf16(Af)[M,K] @ Bt[N,K]^T, 128x128 tile; A staged via regs (convert),
// B staged via global_load_lds.
__global__ __launch_bounds__(256)
void k_gemm_bt(const float* __restrict__ Af, const u16* __restrict__ Bt,
               u16* __restrict__ Cout, int M, int Nout, int K) {
  __shared__ __align__(16) u16 As[128 * 32];
  __shared__ __align__(16) u16 Bs[128 * 32];
  const int tid = threadIdx.x;
  const int l = tid & 63;
  const int w = tid >> 6;
  const int mBase = blockIdx.x * 128;
  const int nBase = blockIdx.y * 128;
  const int wm = (w >> 1) * 64;
  const int wn = (w & 1) * 64;
  const int lrow = l >> 2;
  const int lcol = (l & 3) * 8;
  const int q = l >> 4;
  const int r = l & 15;
  f32x4 acc[4][4] = {};

  for (int k0 = 0; k0 < K; k0 += 32) {
    #pragma unroll
    for (int p = 0; p < 2; p++) {
      int row = w * 32 + p * 16 + lrow;
      const float4* fp = (const float4*)(Af + (size_t)(mBase + row) * K + k0 + lcol);
      float4 x = fp[0], y = fp[1];
      async16(Bt + (size_t)(nBase + row) * K + k0 + lcol, (char*)Bs + w * 2048 + p * 1024);
      uint4 o;
      o.x = pack2(x.x, x.y); o.y = pack2(x.z, x.w);
      o.z = pack2(y.x, y.y); o.w = pack2(y.z, y.w);
      *(uint4*)((char*)As + w * 2048 + p * 1024 + l * 16) = o;
    }
    __syncthreads();
    bf16x8 af[4], bfr[4];
    #pragma unroll
    for (int i = 0; i < 4; i++) af[i] = *(const bf16x8*)&As[(wm + i * 16 + r) * 32 + q * 8];
    #pragma unroll
    for (int j = 0; j < 4; j++) bfr[j] = *(const bf16x8*)&Bs[(wn + j * 16 + r) * 32 + q * 8];
    #pragma unroll
    for (int i = 0; i < 4; i++)
      #pragma unroll
      for (int j = 0; j < 4; j++)
        acc[i][j] = MFMA16(af[i], bfr[j], acc[i][j], 0, 0, 0);
    __syncthreads();
  }

  #pragma unroll
  for (int i = 0; i < 4; i++) {
    #pragma unroll
    for (int j = 0; j < 4; j++) {
      int col = nBase + wn + j * 16 + r;
      #pragma unroll
      for (int reg = 0; reg < 4; reg++) {
        int rowg = mBase + wm + i * 16 + q * 4 + reg;
        Cout[(size_t)rowg * Nout + col] = f2b(acc[i][j][reg]);
      }
    }
  }
}

// ---------------- fused FF chain: 5 stages in one kernel ----------------
// Rows are independent across the whole chain -> 32 blocks x 16 graph-rows,
// activations ping-pong in LDS (stride 520 to break bank aliasing), weights
// streamed from L2 (512 KB each, shared by all blocks).
// g = sigmoid(q@W1+b1); z1..z3 = relu chain; out = z3 + g@Ws + bs (f32).
__global__ __launch_bounds__(256)
void k_ff(const u16* __restrict__ qb,
          const u16* __restrict__ w1t, const float* __restrict__ b1,
          const u16* __restrict__ gw1t, const float* __restrict__ gb1,
          const u16* __restrict__ gw2t, const float* __restrict__ gb2,
          const u16* __restrict__ gw3t, const float* __restrict__ gb3,
          const u16* __restrict__ gwst, const float* __restrict__ gbs,
          float* __restrict__ osmall) {
  __shared__ __align__(16) u16 bufX[16 * 520];
  __shared__ __align__(16) u16 bufY[16 * 520];
  __shared__ __align__(16) u16 bufG[16 * 520];
  const int tid = threadIdx.x;
  const int l = tid & 63;
  const int w = tid >> 6;
  const int q = l >> 4;
  const int r = l & 15;
  const int rb = blockIdx.x * 16;

  for (int idx = tid; idx < 16 * 64; idx += 256) {
    int row = idx >> 6, c8 = (idx & 63) * 8;
    *(uint4*)&bufX[row * 520 + c8] = *(const uint4*)(qb + (size_t)(rb + row) * DIM + c8);
  }
  __syncthreads();

  // mode: 0 = sigmoid->dst, 1 = relu->dst, 2 = final (add addY, f32->osmall)
  auto stage = [&](const u16* A, const u16* Wt, const float* bias, int mode,
                   const u16* addY, u16* dst) {
    f32x4 acc[8] = {};
    for (int k0 = 0; k0 < DIM; k0 += 32) {
      bf16x8 af = *(const bf16x8*)&A[r * 520 + k0 + q * 8];
      #pragma unroll
      for (int j = 0; j < 8; j++) {
        bf16x8 bf = *(const bf16x8*)(Wt + (size_t)(w * 128 + j * 16 + r) * DIM + k0 + q * 8);
        acc[j] = MFMA16(af, bf, acc[j], 0, 0, 0);
      }
    }
    #pragma unroll
    for (int j = 0; j < 8; j++) {
      int col = w * 128 + j * 16 + r;
      float bv = bias[col];
      #pragma unroll
      for (int reg = 0; reg < 4; reg++) {
        int row = q * 4 + reg;
        float v = acc[j][reg] + bv;
        if (mode == 0) v = 1.0f / (1.0f + expf(-v));
        else if (mode == 1) v = fmaxf(v, 0.0f);
        else {
          v += b2f(addY[row * 520 + col]);
          osmall[(size_t)(rb + row) * DIM + col] = v;
          continue;
        }
        dst[row * 520 + col] = f2b(v);
      }
    }
    __syncthreads();
  };

  stage(bufX, w1t,  b1,  0, nullptr, bufG);   // g  = sigmoid(q @ W1 + b1)
  stage(bufG, gw1t, gb1, 1, nullptr, bufY);   // z1 = relu(g @ gW1 + gb1)
  stage(bufY, gw2t, gb2, 1, nullptr, bufX);   // z2 = relu(z1 @ gW2 + gb2)
  stage(bufX, gw3t, gb3, 1, nullptr, bufY);   // z3 = relu(z2 @ gW3 + gb3)
  stage(bufG, gwst, gbs, 2, bufY,    nullptr);// out = z3 + g @ gWs + gbs
}

// ---------------- sparse aggregation: XCD-affine column slicing + LDS edges ----
template <bool RELU, bool POOL>
__global__ __launch_bounds__(256)
void k_agg(const u16* __restrict__ support, const int* __restrict__ offsets,
           const int2* __restrict__ epack, const float* __restrict__ bias,
           u16* __restrict__ outp) {
  __shared__ int2 eLds[ECAP];
  __shared__ float poolLds[4][64];
  const int chunk = blockIdx.x & 7;
  const int cidx  = blockIdx.x >> 3;       // 0..511
  const int rowBase = cidx * 64;
  const int e0b = offsets[rowBase];
  const int nb = offsets[rowBase + 64] - e0b;
  for (int i = threadIdx.x; i < min(nb, ECAP); i += 256)
    eLds[i] = epack[e0b + i];
  __syncthreads();

  const int wi = threadIdx.x >> 6;
  const int l  = threadIdx.x & 63;
  const int grp = l >> 3;
  const int li  = l & 7;
  const int colOff = chunk * 64 + li * 8;
  const u16* spc = support + colOff;

  f32x2 b[4] = {};
  if (!POOL) {
    const float4* bp = (const float4*)(bias + colOff);
    float4 x = bp[0], y = bp[1];
    b[0] = f32x2{x.x, x.y}; b[1] = f32x2{x.z, x.w};
    b[2] = f32x2{y.x, y.y}; b[3] = f32x2{y.z, y.w};
  }

  f32x2 psum[4] = {};

  #pragma unroll
  for (int pass = 0; pass < 2; pass++) {
    int r = rowBase + wi * 16 + pass * 8 + grp;
    int re0 = offsets[r] - e0b;
    int deg = offsets[r + 1] - e0b - re0;

    f32x2 a[4] = {b[0], b[1], b[2], b[3]};

    if (nb <= ECAP) {
      int i = 0;
      for (; i + 8 <= deg; i += 8) {
        int2 p[8];
        u32x4 rr[8];
        #pragma unroll
        for (int u = 0; u < 8; u++) p[u] = eLds[re0 + i + u];
        #pragma unroll
        for (int u = 0; u < 8; u++) rr[u] = *(const u32x4*)(spc + (size_t)p[u].x * DIM);
        #pragma unroll
        for (int u = 0; u < 8; u++) acc8(a, rr[u], __int_as_float(p[u].y));
      }
      for (; i + 4 <= deg; i += 4) {
        int2 p0 = eLds[re0 + i], p1 = eLds[re0 + i + 1];
        int2 p2 = eLds[re0 + i + 2], p3 = eLds[re0 + i + 3];
        u32x4 r0 = *(const u32x4*)(spc + (size_t)p0.x * DIM);
        u32x4 r1 = *(const u32x4*)(spc + (size_t)p1.x * DIM);
        u32x4 r2 = *(const u32x4*)(spc + (size_t)p2.x * DIM);
        u32x4 r3 = *(const u32x4*)(spc + (size_t)p3.x * DIM);
        acc8(a, r0, __int_as_float(p0.y));
        acc8(a, r1, __int_as_float(p1.y));
        acc8(a, r2, __int_as_float(p2.y));
        acc8(a, r3, __int_as_float(p3.y));
      }
      for (; i < deg; i++) {
        int2 p = eLds[re0 + i];
        u32x4 raw = *(const u32x4*)(spc + (size_t)p.x * DIM);
        acc8(a, raw, __int_as_float(p.y));
      }
    } else {
      for (int i = 0; i < deg; i++) {
        int gi = re0 + i;
        int2 p = (gi < ECAP) ? eLds[gi] : epack[e0b + gi];
        u32x4 raw = *(const u32x4*)(spc + (size_t)p.x * DIM);
        acc8(a, raw, __int_as_float(p.y));
      }
    }

    if (POOL) {
      #pragma unroll
      for (int i = 0; i < 4; i++) psum[i] += a[i];
    } else {
      if (RELU) {
        #pragma unroll
        for (int i = 0; i < 4; i++) {
          a[i].x = fmaxf(a[i].x, 0.0f);
          a[i].y = fmaxf(a[i].y, 0.0f);
        }
      }
      u32x4 o;
      o.x = pack2(a[0].x, a[0].y); o.y = pack2(a[1].x, a[1].y);
      o.z = pack2(a[2].x, a[2].y); o.w = pack2(a[3].x, a[3].y);
      *(u32x4*)(outp + (size_t)r * DIM + colOff) = o;
    }
  }

  if (POOL) {
    #pragma unroll
    for (int k = 0; k < 4; k++) {
      psum[k].x += __shfl_xor(psum[k].x, 8);  psum[k].y += __shfl_xor(psum[k].y, 8);
      psum[k].x += __shfl_xor(psum[k].x, 16); psum[k].y += __shfl_xor(psum[k].y, 16);
      psum[k].x += __shfl_xor(psum[k].x, 32); psum[k].y += __shfl_xor(psum[k].y, 32);
    }
    if (grp == 0) {
      #pragma unroll
      for (int k = 0; k < 4; k++) {
        poolLds[wi][li * 8 + 2 * k]     = psum[k].x;
        poolLds[wi][li * 8 + 2 * k + 1] = psum[k].y;
      }
    }
    __syncthreads();
    if (threadIdx.x < 64) {
      int cc = threadIdx.x;
      float s = poolLds[0][cc] + poolLds[1][cc] + poolLds[2][cc] + poolLds[3][cc];
      outp[(size_t)cidx * DIM + chunk * 64 + cc] = f2b(s * (1.0f / 64.0f));
    }
  }
}

// ---------------- expand out_small[G,D] f32 -> out[N,D] f32 ----------------
__global__ void k_expand(const float* __restrict__ small, float* __restrict__ out) {
  int i = blockIdx.x * 256 + threadIdx.x;
  int col4 = i & 127;
  int node = i >> 7;
  float4 v = ((const float4*)small)[((node >> 6) << 7) + col4];
  ((float4*)out)[i] = v;
}

extern "C" void kernel_launch(void* const* d_in, const int* in_sizes, int n_in,
                              void* d_out, int out_size, void* d_ws, size_t ws_size,
                              hipStream_t stream) {
  const float* feat = (const float*)d_in[0];
  const int* src    = (const int*)d_in[1];
  const int* dst    = (const int*)d_in[2];
  const float* adj  = (const float*)d_in[3];
  const float* W0  = (const float*)d_in[5];
  const float* b0  = (const float*)d_in[6];
  const float* W1  = (const float*)d_in[7];
  const float* b1  = (const float*)d_in[8];
  const float* gW1 = (const float*)d_in[9];
  const float* gb1 = (const float*)d_in[10];
  const float* gW2 = (const float*)d_in[11];
  const float* gb2 = (const float*)d_in[12];
  const float* gW3 = (const float*)d_in[13];
  const float* gb3 = (const float*)d_in[14];
  const float* gWs = (const float*)d_in[15];
  const float* gbs = (const float*)d_in[16];

  char* ws = (char*)d_ws;
  size_t off = 0;
  auto alloc = [&](size_t bytes) -> void* {
    void* p = ws + off;
    off = (off + bytes + 255) & ~(size_t)255;
    return p;
  };
  u16* bufA = (u16*)alloc((size_t)N_NODES * DIM * 2);   // h1
  u16* bufB = (u16*)alloc((size_t)N_NODES * DIM * 2);   // support0
  u16* wt[6];
  for (int i = 0; i < 6; i++) wt[i] = (u16*)alloc((size_t)DIM * DIM * 2);
  int* counts   = (int*)alloc((size_t)N_NODES * 4);
  int* offsets  = (int*)alloc((size_t)(N_NODES + 1) * 4);
  int* cursor   = (int*)alloc((size_t)N_NODES * 4);
  int2* epack   = (int2*)alloc((size_t)N_EDGES * 8);
  u16* qb       = (u16*)alloc((size_t)N_GRAPHS * DIM * 2);
  float* osmall = (float*)alloc((size_t)N_GRAPHS * DIM * 4);

  (void)hipMemsetAsync(counts, 0, (size_t)N_NODES * 4, stream);

  WPack wp;
  wp.src[0] = W0; wp.src[1] = W1; wp.src[2] = gW1; wp.src[3] = gW2; wp.src[4] = gW3; wp.src[5] = gWs;
  for (int i = 0; i < 6; i++) wp.dst[i] = wt[i];

  k_prep<<<NB_TR + N_EDGES / 256, 256, 0, stream>>>(wp, dst, counts);
  k_scan<<<1, 1024, 0, stream>>>(counts, offsets, cursor);
  k_fill<<<N_EDGES / 256, 256, 0, stream>>>(src, dst, adj, cursor, epack);

  // support0 = bf16(feat) @ W0   (conversion fused into staging)
  k_gemm_bt<<<dim3(N_NODES / 128, DIM / 128), 256, 0, stream>>>(feat, wt[0], bufB, N_NODES, DIM, DIM);
  // h1 = relu(A_hat @ support0 + b0)
  k_agg<true, false><<<4096, 256, 0, stream>>>(bufB, offsets, epack, b0, bufA);
  // q[g] = (1/64) sum val_e * h1[src_e]   (mean commuted past @W1)
  k_agg<false, true><<<4096, 256, 0, stream>>>(bufA, offsets, epack, nullptr, qb);
  // full FF chain in one kernel
  k_ff<<<32, 256, 0, stream>>>(qb, wt[1], b1, wt[2], gb1, wt[3], gb2, wt[4], gb3, wt[5], gbs, osmall);

  k_expand<<<(N_NODES * DIM / 4) / 256, 256, 0, stream>>>(osmall, (float*)d_out);
}

// Round 12
// 426.273 us; speedup vs baseline: 1.1834x; 1.1834x over previous
//
#include <hip/hip_runtime.h>

typedef unsigned int u32;
typedef unsigned short u16;

typedef __attribute__((ext_vector_type(8))) __bf16 bf16x8;
typedef __attribute__((ext_vector_type(4))) float f32x4;
typedef __attribute__((ext_vector_type(2))) float f32x2;
typedef __attribute__((ext_vector_type(4))) u32 u32x4;

#define N_NODES 32768
#define N_EDGES 524288
#define DIM 512
#define N_GRAPHS 512
#define ECAP 1536   // staged edges per 64-row block (12 KB); mean 1024, +16 sigma
#define NB_TR 1536

#define MFMA16 __builtin_amdgcn_mfma_f32_16x16x32_bf16

__device__ __forceinline__ u16 f2b(float f) {
  union { float f; u32 u; } v; v.f = f;
  u32 r = v.u + 0x7FFFu + ((v.u >> 16) & 1u);   // RNE
  return (u16)(r >> 16);
}
__device__ __forceinline__ u32 pack2(float a, float b) {
  return (u32)f2b(a) | ((u32)f2b(b) << 16);
}
__device__ __forceinline__ float blo(u32 u) { union { u32 u; float f; } v; v.u = u << 16; return v.f; }
__device__ __forceinline__ float bhi(u32 u) { union { u32 u; float f; } v; v.u = u & 0xFFFF0000u; return v.f; }
__device__ __forceinline__ float b2f(u16 u) { union { u32 u; float f; } v; v.u = ((u32)u) << 16; return v.f; }

__device__ __forceinline__ void async16(const void* g, void* l) {
  __builtin_amdgcn_global_load_lds(
      (const __attribute__((address_space(1))) u32*)g,
      (__attribute__((address_space(3))) u32*)l, 16, 0, 0);
}

__device__ __forceinline__ void acc8(f32x2* a, u32x4 raw, float v) {
  f32x2 v2 = {v, v};
  a[0] += v2 * f32x2{blo(raw.x), bhi(raw.x)};
  a[1] += v2 * f32x2{blo(raw.y), bhi(raw.y)};
  a[2] += v2 * f32x2{blo(raw.z), bhi(raw.z)};
  a[3] += v2 * f32x2{blo(raw.w), bhi(raw.w)};
}

// ---------------- prep: 6 weight transposes + dst histogram ----------------
struct WPack {
  const float* src[6];
  u16* dst[6];
};
__global__ __launch_bounds__(256)
void k_prep(WPack wp, const int* __restrict__ dstv, int* __restrict__ counts) {
  __shared__ float tile[32][33];
  const int bid = blockIdx.x, tid = threadIdx.x;
  if (bid < NB_TR) {
    int bz = bid >> 8, rem = bid & 255, by = rem >> 4, bx = rem & 15;
    const float* W = wp.src[bz];
    u16* Wt = wp.dst[bz];
    int tx = tid & 31, ty = tid >> 5;
    int bx32 = bx * 32, by32 = by * 32;
    #pragma unroll
    for (int i = 0; i < 4; i++)
      tile[ty + 8 * i][tx] = W[(size_t)(by32 + ty + 8 * i) * DIM + bx32 + tx];
    __syncthreads();
    #pragma unroll
    for (int i = 0; i < 4; i++)
      Wt[(size_t)(bx32 + ty + 8 * i) * DIM + by32 + tx] = f2b(tile[tx][ty + 8 * i]);
  } else {
    int i = (bid - NB_TR) * 256 + tid;
    atomicAdd(&counts[dstv[i]], 1);
  }
}

// ---------------- CSR scan (int4-vectorized) ----------------
__global__ void k_scan(const int* __restrict__ counts, int* __restrict__ offsets,
                       int* __restrict__ cursor) {
  __shared__ int part[1024];
  int t = threadIdx.x;
  const int4* c4 = (const int4*)counts;
  int4 cv[8];
  #pragma unroll
  for (int j = 0; j < 8; j++) cv[j] = c4[t * 8 + j];
  int loc[32];
  int s = 0;
  #pragma unroll
  for (int j = 0; j < 8; j++) {
    loc[4 * j + 0] = s; s += cv[j].x;
    loc[4 * j + 1] = s; s += cv[j].y;
    loc[4 * j + 2] = s; s += cv[j].z;
    loc[4 * j + 3] = s; s += cv[j].w;
  }
  part[t] = s;
  __syncthreads();
  for (int off = 1; off < 1024; off <<= 1) {
    int v = (t >= off) ? part[t - off] : 0;
    __syncthreads();
    part[t] += v;
    __syncthreads();
  }
  int excl = (t == 0) ? 0 : part[t - 1];
  #pragma unroll
  for (int j = 0; j < 8; j++) {
    int4 o = make_int4(excl + loc[4 * j], excl + loc[4 * j + 1],
                       excl + loc[4 * j + 2], excl + loc[4 * j + 3]);
    ((int4*)offsets)[t * 8 + j] = o;
    ((int4*)cursor)[t * 8 + j] = o;
  }
  if (t == 1023) offsets[N_NODES] = excl + s;
}

__global__ void k_fill(const int* __restrict__ src, const int* __restrict__ dst,
                       const float* __restrict__ vals, int* __restrict__ cursor,
                       int2* __restrict__ epack) {
  int i = blockIdx.x * 256 + threadIdx.x;
  if (i >= N_EDGES) return;
  int d = dst[i];
  int p = atomicAdd(&cursor[d], 1);
  epack[p] = make_int2(src[i], __float_as_int(vals[i]));
}

// ---------------- big GEMM with fused f32->bf16 A-conversion ----------------
__global__ __launch_bounds__(256)
void k_gemm_bt(const float* __restrict__ Af, const u16* __restrict__ Bt,
               u16* __restrict__ Cout, int M, int Nout, int K) {
  __shared__ __align__(16) u16 As[128 * 32];
  __shared__ __align__(16) u16 Bs[128 * 32];
  const int tid = threadIdx.x;
  const int l = tid & 63;
  const int w = tid >> 6;
  const int mBase = blockIdx.x * 128;
  const int nBase = blockIdx.y * 128;
  const int wm = (w >> 1) * 64;
  const int wn = (w & 1) * 64;
  const int lrow = l >> 2;
  const int lcol = (l & 3) * 8;
  const int q = l >> 4;
  const int r = l & 15;
  f32x4 acc[4][4] = {};

  for (int k0 = 0; k0 < K; k0 += 32) {
    #pragma unroll
    for (int p = 0; p < 2; p++) {
      int row = w * 32 + p * 16 + lrow;
      const float4* fp = (const float4*)(Af + (size_t)(mBase + row) * K + k0 + lcol);
      float4 x = fp[0], y = fp[1];
      async16(Bt + (size_t)(nBase + row) * K + k0 + lcol, (char*)Bs + w * 2048 + p * 1024);
      uint4 o;
      o.x = pack2(x.x, x.y); o.y = pack2(x.z, x.w);
      o.z = pack2(y.x, y.y); o.w = pack2(y.z, y.w);
      *(uint4*)((char*)As + w * 2048 + p * 1024 + l * 16) = o;
    }
    __syncthreads();
    bf16x8 af[4], bfr[4];
    #pragma unroll
    for (int i = 0; i < 4; i++) af[i] = *(const bf16x8*)&As[(wm + i * 16 + r) * 32 + q * 8];
    #pragma unroll
    for (int j = 0; j < 4; j++) bfr[j] = *(const bf16x8*)&Bs[(wn + j * 16 + r) * 32 + q * 8];
    #pragma unroll
    for (int i = 0; i < 4; i++)
      #pragma unroll
      for (int j = 0; j < 4; j++)
        acc[i][j] = MFMA16(af[i], bfr[j], acc[i][j], 0, 0, 0);
    __syncthreads();
  }

  #pragma unroll
  for (int i = 0; i < 4; i++) {
    #pragma unroll
    for (int j = 0; j < 4; j++) {
      int col = nBase + wn + j * 16 + r;
      #pragma unroll
      for (int reg = 0; reg < 4; reg++) {
        int rowg = mBase + wm + i * 16 + q * 4 + reg;
        Cout[(size_t)rowg * Nout + col] = f2b(acc[i][j][reg]);
      }
    }
  }
}

// ---------------- fused FF chain: 5 stages, LDS double-buffered weight staging ----
// 32 blocks x 16 graph-rows. Per k-step: stage next 32-k weight strip (32 KB)
// via global_load_lds into the other buffer AFTER the barrier, then MFMA the
// current strip -> loads get the MFMA phase + barrier gap to complete.
__global__ __launch_bounds__(256)
void k_ff(const u16* __restrict__ qb,
          const u16* __restrict__ w1t, const float* __restrict__ b1,
          const u16* __restrict__ gw1t, const float* __restrict__ gb1,
          const u16* __restrict__ gw2t, const float* __restrict__ gb2,
          const u16* __restrict__ gw3t, const float* __restrict__ gb3,
          const u16* __restrict__ gwst, const float* __restrict__ gbs,
          float* __restrict__ osmall) {
  __shared__ __align__(16) u16 bufX[16 * 520];
  __shared__ __align__(16) u16 bufY[16 * 520];
  __shared__ __align__(16) u16 bufG[16 * 520];
  __shared__ __align__(16) u16 wbuf[2][512 * 32];
  const int tid = threadIdx.x;
  const int l = tid & 63;
  const int w = tid >> 6;
  const int q = l >> 4;
  const int r = l & 15;
  const int rb = blockIdx.x * 16;

  for (int idx = tid; idx < 16 * 64; idx += 256) {
    int row = idx >> 6, c8 = (idx & 63) * 8;
    *(uint4*)&bufX[row * 520 + c8] = *(const uint4*)(qb + (size_t)(rb + row) * DIM + c8);
  }

  // stage Wt[:, kb..kb+32) (32 KB) into wbuf[buf]; LDS layout row*64B + k*2B
  auto stageW = [&](const u16* Wt, int kb, int buf) {
    char* base = (char*)&wbuf[buf][0] + w * 1024;
    const u16* gp = Wt + (size_t)(w * 16 + (l >> 2)) * DIM + kb + (l & 3) * 8;
    #pragma unroll
    for (int s = 0; s < 8; s++)
      async16(gp + (size_t)s * 64 * DIM, base + s * 4096);
  };

  // mode: 0 = sigmoid->dst, 1 = relu->dst, 2 = final (add addY, f32->osmall)
  auto stage = [&](const u16* A, const u16* Wt, const float* bias, int mode,
                   const u16* addY, u16* dst) {
    f32x4 acc[8] = {};
    stageW(Wt, 0, 0);
    for (int k0 = 0; k0 < DIM; k0 += 32) {
      int cur = (k0 >> 5) & 1;
      __syncthreads();                      // wbuf[cur] ready (drains vmcnt)
      if (k0 + 32 < DIM) stageW(Wt, k0 + 32, cur ^ 1);   // prefetch, overlaps MFMAs
      bf16x8 af = *(const bf16x8*)&A[r * 520 + k0 + q * 8];
      const u16* wb = &wbuf[cur][0];
      #pragma unroll
      for (int j = 0; j < 8; j++) {
        bf16x8 bf = *(const bf16x8*)&wb[(w * 128 + j * 16 + r) * 32 + q * 8];
        acc[j] = MFMA16(af, bf, acc[j], 0, 0, 0);
      }
    }
    #pragma unroll
    for (int j = 0; j < 8; j++) {
      int col = w * 128 + j * 16 + r;
      float bv = bias[col];
      #pragma unroll
      for (int reg = 0; reg < 4; reg++) {
        int row = q * 4 + reg;
        float v = acc[j][reg] + bv;
        if (mode == 0) v = 1.0f / (1.0f + expf(-v));
        else if (mode == 1) v = fmaxf(v, 0.0f);
        else {
          v += b2f(addY[row * 520 + col]);
          osmall[(size_t)(rb + row) * DIM + col] = v;
          continue;
        }
        dst[row * 520 + col] = f2b(v);
      }
    }
    __syncthreads();
  };

  stage(bufX, w1t,  b1,  0, nullptr, bufG);   // g  = sigmoid(q @ W1 + b1)
  stage(bufG, gw1t, gb1, 1, nullptr, bufY);   // z1 = relu(g @ gW1 + gb1)
  stage(bufY, gw2t, gb2, 1, nullptr, bufX);   // z2 = relu(z1 @ gW2 + gb2)
  stage(bufX, gw3t, gb3, 1, nullptr, bufY);   // z3 = relu(z2 @ gW3 + gb3)
  stage(bufG, gwst, gbs, 2, bufY,    nullptr);// out = z3 + g @ gWs + gbs
}

// ---------------- sparse aggregation: XCD-affine column slicing + LDS edges ----
template <bool RELU, bool POOL>
__global__ __launch_bounds__(256)
void k_agg(const u16* __restrict__ support, const int* __restrict__ offsets,
           const int2* __restrict__ epack, const float* __restrict__ bias,
           u16* __restrict__ outp) {
  __shared__ int2 eLds[ECAP];
  __shared__ float poolLds[4][64];
  const int chunk = blockIdx.x & 7;
  const int cidx  = blockIdx.x >> 3;       // 0..511
  const int rowBase = cidx * 64;
  const int e0b = offsets[rowBase];
  const int nb = offsets[rowBase + 64] - e0b;
  for (int i = threadIdx.x; i < min(nb, ECAP); i += 256)
    eLds[i] = epack[e0b + i];
  __syncthreads();

  const int wi = threadIdx.x >> 6;
  const int l  = threadIdx.x & 63;
  const int grp = l >> 3;
  const int li  = l & 7;
  const int colOff = chunk * 64 + li * 8;
  const u16* spc = support + colOff;

  f32x2 b[4] = {};
  if (!POOL) {
    const float4* bp = (const float4*)(bias + colOff);
    float4 x = bp[0], y = bp[1];
    b[0] = f32x2{x.x, x.y}; b[1] = f32x2{x.z, x.w};
    b[2] = f32x2{y.x, y.y}; b[3] = f32x2{y.z, y.w};
  }

  f32x2 psum[4] = {};

  #pragma unroll
  for (int pass = 0; pass < 2; pass++) {
    int r = rowBase + wi * 16 + pass * 8 + grp;
    int re0 = offsets[r] - e0b;
    int deg = offsets[r + 1] - e0b - re0;

    f32x2 a[4] = {b[0], b[1], b[2], b[3]};

    if (nb <= ECAP) {
      int i = 0;
      for (; i + 8 <= deg; i += 8) {
        int2 p[8];
        u32x4 rr[8];
        #pragma unroll
        for (int u = 0; u < 8; u++) p[u] = eLds[re0 + i + u];
        #pragma unroll
        for (int u = 0; u < 8; u++) rr[u] = *(const u32x4*)(spc + (size_t)p[u].x * DIM);
        #pragma unroll
        for (int u = 0; u < 8; u++) acc8(a, rr[u], __int_as_float(p[u].y));
      }
      for (; i + 4 <= deg; i += 4) {
        int2 p0 = eLds[re0 + i], p1 = eLds[re0 + i + 1];
        int2 p2 = eLds[re0 + i + 2], p3 = eLds[re0 + i + 3];
        u32x4 r0 = *(const u32x4*)(spc + (size_t)p0.x * DIM);
        u32x4 r1 = *(const u32x4*)(spc + (size_t)p1.x * DIM);
        u32x4 r2 = *(const u32x4*)(spc + (size_t)p2.x * DIM);
        u32x4 r3 = *(const u32x4*)(spc + (size_t)p3.x * DIM);
        acc8(a, r0, __int_as_float(p0.y));
        acc8(a, r1, __int_as_float(p1.y));
        acc8(a, r2, __int_as_float(p2.y));
        acc8(a, r3, __int_as_float(p3.y));
      }
      for (; i < deg; i++) {
        int2 p = eLds[re0 + i];
        u32x4 raw = *(const u32x4*)(spc + (size_t)p.x * DIM);
        acc8(a, raw, __int_as_float(p.y));
      }
    } else {
      for (int i = 0; i < deg; i++) {
        int gi = re0 + i;
        int2 p = (gi < ECAP) ? eLds[gi] : epack[e0b + gi];
        u32x4 raw = *(const u32x4*)(spc + (size_t)p.x * DIM);
        acc8(a, raw, __int_as_float(p.y));
      }
    }

    if (POOL) {
      #pragma unroll
      for (int i = 0; i < 4; i++) psum[i] += a[i];
    } else {
      if (RELU) {
        #pragma unroll
        for (int i = 0; i < 4; i++) {
          a[i].x = fmaxf(a[i].x, 0.0f);
          a[i].y = fmaxf(a[i].y, 0.0f);
        }
      }
      u32x4 o;
      o.x = pack2(a[0].x, a[0].y); o.y = pack2(a[1].x, a[1].y);
      o.z = pack2(a[2].x, a[2].y); o.w = pack2(a[3].x, a[3].y);
      *(u32x4*)(outp + (size_t)r * DIM + colOff) = o;
    }
  }

  if (POOL) {
    #pragma unroll
    for (int k = 0; k < 4; k++) {
      psum[k].x += __shfl_xor(psum[k].x, 8);  psum[k].y += __shfl_xor(psum[k].y, 8);
      psum[k].x += __shfl_xor(psum[k].x, 16); psum[k].y += __shfl_xor(psum[k].y, 16);
      psum[k].x += __shfl_xor(psum[k].x, 32); psum[k].y += __shfl_xor(psum[k].y, 32);
    }
    if (grp == 0) {
      #pragma unroll
      for (int k = 0; k < 4; k++) {
        poolLds[wi][li * 8 + 2 * k]     = psum[k].x;
        poolLds[wi][li * 8 + 2 * k + 1] = psum[k].y;
      }
    }
    __syncthreads();
    if (threadIdx.x < 64) {
      int cc = threadIdx.x;
      float s = poolLds[0][cc] + poolLds[1][cc] + poolLds[2][cc] + poolLds[3][cc];
      outp[(size_t)cidx * DIM + chunk * 64 + cc] = f2b(s * (1.0f / 64.0f));
    }
  }
}

// ---------------- expand out_small[G,D] f32 -> out[N,D] f32 ----------------
__global__ void k_expand(const float* __restrict__ small, float* __restrict__ out) {
  int i = blockIdx.x * 256 + threadIdx.x;
  int col4 = i & 127;
  int node = i >> 7;
  float4 v = ((const float4*)small)[((node >> 6) << 7) + col4];
  ((float4*)out)[i] = v;
}

extern "C" void kernel_launch(void* const* d_in, const int* in_sizes, int n_in,
                              void* d_out, int out_size, void* d_ws, size_t ws_size,
                              hipStream_t stream) {
  const float* feat = (const float*)d_in[0];
  const int* src    = (const int*)d_in[1];
  const int* dst    = (const int*)d_in[2];
  const float* adj  = (const float*)d_in[3];
  const float* W0  = (const float*)d_in[5];
  const float* b0  = (const float*)d_in[6];
  const float* W1  = (const float*)d_in[7];
  const float* b1  = (const float*)d_in[8];
  const float* gW1 = (const float*)d_in[9];
  const float* gb1 = (const float*)d_in[10];
  const float* gW2 = (const float*)d_in[11];
  const float* gb2 = (const float*)d_in[12];
  const float* gW3 = (const float*)d_in[13];
  const float* gb3 = (const float*)d_in[14];
  const float* gWs = (const float*)d_in[15];
  const float* gbs = (const float*)d_in[16];

  char* ws = (char*)d_ws;
  size_t off = 0;
  auto alloc = [&](size_t bytes) -> void* {
    void* p = ws + off;
    off = (off + bytes + 255) & ~(size_t)255;
    return p;
  };
  u16* bufA = (u16*)alloc((size_t)N_NODES * DIM * 2);   // h1
  u16* bufB = (u16*)alloc((size_t)N_NODES * DIM * 2);   // support0
  u16* wt[6];
  for (int i = 0; i < 6; i++) wt[i] = (u16*)alloc((size_t)DIM * DIM * 2);
  int* counts   = (int*)alloc((size_t)N_NODES * 4);
  int* offsets  = (int*)alloc((size_t)(N_NODES + 1) * 4);
  int* cursor   = (int*)alloc((size_t)N_NODES * 4);
  int2* epack   = (int2*)alloc((size_t)N_EDGES * 8);
  u16* qb       = (u16*)alloc((size_t)N_GRAPHS * DIM * 2);
  float* osmall = (float*)alloc((size_t)N_GRAPHS * DIM * 4);

  (void)hipMemsetAsync(counts, 0, (size_t)N_NODES * 4, stream);

  WPack wp;
  wp.src[0] = W0; wp.src[1] = W1; wp.src[2] = gW1; wp.src[3] = gW2; wp.src[4] = gW3; wp.src[5] = gWs;
  for (int i = 0; i < 6; i++) wp.dst[i] = wt[i];

  k_prep<<<NB_TR + N_EDGES / 256, 256, 0, stream>>>(wp, dst, counts);
  k_scan<<<1, 1024, 0, stream>>>(counts, offsets, cursor);
  k_fill<<<N_EDGES / 256, 256, 0, stream>>>(src, dst, adj, cursor, epack);

  // support0 = bf16(feat) @ W0   (conversion fused into staging)
  k_gemm_bt<<<dim3(N_NODES / 128, DIM / 128), 256, 0, stream>>>(feat, wt[0], bufB, N_NODES, DIM, DIM);
  // h1 = relu(A_hat @ support0 + b0)
  k_agg<true, false><<<4096, 256, 0, stream>>>(bufB, offsets, epack, b0, bufA);
  // q[g] = (1/64) sum val_e * h1[src_e]   (mean commuted past @W1)
  k_agg<false, true><<<4096, 256, 0, stream>>>(bufA, offsets, epack, nullptr, qb);
  // full FF chain in one kernel (dbuf weight staging)
  k_ff<<<32, 256, 0, stream>>>(qb, wt[1], b1, wt[2], gb1, wt[3], gb2, wt[4], gb3, wt[5], gbs, osmall);

  k_expand<<<(N_NODES * DIM / 4) / 256, 256, 0, stream>>>(osmall, (float*)d_out);
}